// Round 1
// 353.400 us; speedup vs baseline: 1.0347x; 1.0347x over previous
//
#include <hip/hip_runtime.h>

// Conv2d VALID 3x3: x[32][64][112][112] f32, w[128][64][3][3] f32 -> out[32][128][110][110] f32
// Implicit GEMM on bf16 MFMA 16x16x32. Block: 128co x 256px (16oh x 16ow), 8 waves (512 thr).
// R4: W is NOT staged to LDS. wp is 144 KB = permanently L2-resident; it is pre-permuted so each
//     wave's A-fragment is ONE coalesced 1 KB global_load_dwordx4 (base + lane*16B). This removes
//     wpl (18 KB LDS) and ALL 18 per-plane barriers -> single barrier per block, LDS = xwin only
//     (46.6 KB) -> 2 blocks * 8 waves = 16 waves/CU (2x occupancy). acc per wave shrinks to 4x4
//     (64 VGPR) so __launch_bounds__(512,4) can hold 4 waves/SIMD. Waves run independently after
//     the staging barrier -> s_setprio(1) around the MFMA cluster (attn-like regime, m191).

typedef short bf16x8 __attribute__((ext_vector_type(8)));
typedef float f32x4 __attribute__((ext_vector_type(4)));

__device__ __forceinline__ unsigned short f2bf(float f) {
    unsigned int u = __builtin_bit_cast(unsigned int, f);
    unsigned int r = u + 0x7fffu + ((u >> 16) & 1u);   // RNE
    return (unsigned short)(r >> 16);
}
__device__ __forceinline__ unsigned int pack2(float lo, float hi) {
    return (unsigned)f2bf(lo) | ((unsigned)f2bf(hi) << 16);
}

// wp layout (bf16x8 units of 16B): unit = ((r*8 + cog)*2 + cs)*64 + lane, lane = quad*16 + l15.
// wp[unit*8 + e] = bf16(W[co = cog*16 + l15][ci = cs*32 + quad*8 + e][kh = r/3][kw = r%3])
// -> a wave's fragment load for (r, cog, cs) is one contiguous 1024 B global_load_dwordx4.
__global__ void wperm_kernel(const float* __restrict__ W, unsigned short* __restrict__ wp) {
    int t = blockIdx.x * 256 + threadIdx.x;
    if (t < 73728) {
        int e    = t & 7;
        int l15  = (t >> 3) & 15;
        int quad = (t >> 7) & 3;
        int cs   = (t >> 9) & 1;
        int cog  = (t >> 10) & 7;
        int r    = t >> 13;
        int ci = cs * 32 + quad * 8 + e;
        int co = cog * 16 + l15;
        wp[t] = f2bf(W[(co * 64 + ci) * 9 + r]);
    }
}

__global__ __launch_bounds__(512, 4) void conv_mfma(const float* __restrict__ x,
                                                    const unsigned short* __restrict__ wp,
                                                    float* __restrict__ out) {
    // pixel/row stride 72 shorts = 144 B (36 dw == 4 mod 32 banks): conflict-free b128 reads
    __shared__ alignas(16) unsigned short xwin[324 * 72];   // 18x18 px * (64ci+8pad) = 46656 B

    const int tid  = threadIdx.x;
    const int lane = tid & 63;
    const int wv   = tid >> 6;          // 0..7
    const int wvoh = wv & 3;            // oh quarter
    const int wvco = wv >> 1 & 0;       // placeholder (see below)
    const int quad = lane >> 4;
    const int l15  = lane & 15;

    // 8 waves = 2 co-halves x 4 oh-quarters
    const int wco  = wv >> 2;           // 0..1 : co half (64 co each)
    const int woh  = wv & 3;            // 0..3 : 4 oh rows each
    (void)wvoh; (void)wvco;

    // XCD swizzle: blocks with idx%8==xcd land on the same XCD; give each XCD whole batches
    // so the 49 tiles of a batch (x = 3.2 MB < 4 MB L2) are co-resident -> halo L2 hits.
    const int blk  = blockIdx.x;            // 1568 = 8 xcd * 196 slots
    const int xcd  = blk & 7;
    const int slot = blk >> 3;              // 0..195
    const int b    = xcd + 8 * (slot / 49);
    const int tile = slot % 49;
    const int oh0  = (tile / 7) * 16;
    const int ow0  = (tile % 7) * 16;

    const float* xb = x + b * 802816;                       // 64*12544

    // ---- stage x window: cols 0..15 via float4 pairs (2 adjacent ci planes) ----
    for (int t = tid; t < 2304; t += 512) {
        const int cgl = t & 7;
        const int hwl = (t >> 3) & 7;
        const int cgh = (t >> 6) & 3;
        const int hwh = t >> 8;                             // 0..8
        const int cg  = cgh * 8 + cgl;                      // ci pair = 2cg, 2cg+1
        const int hw  = hwh * 8 + hwl;                      // 0..71
        const int hh  = hw >> 2;                            // 0..17
        const int wc  = hw & 3;                             // cols wc*4..+3
        const int h   = min(oh0 + hh, 111);                 // clamped rows feed only discarded oh
        const float* p0 = xb + (2 * cg) * 12544 + h * 112 + ow0 + wc * 4;
        const f32x4 a = *reinterpret_cast<const f32x4*>(p0);
        const f32x4 c = *reinterpret_cast<const f32x4*>(p0 + 12544);
        unsigned int* dst = reinterpret_cast<unsigned int*>(
            &xwin[(hh * 18 + wc * 4) * 72 + 2 * cg]);
        dst[0]   = pack2(a[0], c[0]);
        dst[36]  = pack2(a[1], c[1]);
        dst[72]  = pack2(a[2], c[2]);
        dst[108] = pack2(a[3], c[3]);
    }
    // ---- halo cols 16,17 (clamped: garbage only feeds discarded ow) ----
    for (int u = tid; u < 576; u += 512) {
        const int cg  = u & 31;
        const int hh  = u >> 5;
        const int h   = min(oh0 + hh, 111);
        const int w16 = min(ow0 + 16, 111);
        const int w17 = min(ow0 + 17, 111);
        const float* p0 = xb + (2 * cg) * 12544 + h * 112;
        unsigned int* dst = reinterpret_cast<unsigned int*>(
            &xwin[(hh * 18 + 16) * 72 + 2 * cg]);
        dst[0]  = pack2(p0[w16], p0[12544 + w16]);
        dst[36] = pack2(p0[w17], p0[12544 + w17]);
    }

    f32x4 acc[4][4];
    const f32x4 zero = {0.0f, 0.0f, 0.0f, 0.0f};
    #pragma unroll
    for (int mt = 0; mt < 4; mt++)
        #pragma unroll
        for (int nt = 0; nt < 4; nt++) acc[mt][nt] = zero;

    __syncthreads();   // the ONLY barrier: xwin ready; K-loop below is barrier-free

    // per-thread W base: fragment (r, cog, cs) lives at wq[((r*8+cog)*2+cs)*64]
    const bf16x8* wq = reinterpret_cast<const bf16x8*>(wp) + lane;
    const int cogb = wco * 4;

    #pragma unroll
    for (int r = 0; r < 9; r++) {
        const int kh = r / 3;
        const int kw = r % 3;
        #pragma unroll
        for (int cs = 0; cs < 2; cs++) {
            const int ko = cs * 32 + quad * 8;
            bf16x8 af[4];
            #pragma unroll
            for (int mt = 0; mt < 4; mt++)
                af[mt] = wq[((r * 8 + cogb + mt) * 2 + cs) * 64];   // coalesced 1KB, L1/L2-hit
            bf16x8 bfrag[4];
            #pragma unroll
            for (int nt = 0; nt < 4; nt++)
                bfrag[nt] = *reinterpret_cast<const bf16x8*>(
                    &xwin[((woh * 4 + nt + kh) * 18 + (l15 + kw)) * 72 + ko]);
            __builtin_amdgcn_s_setprio(1);
            #pragma unroll
            for (int mt = 0; mt < 4; mt++)
                #pragma unroll
                for (int nt = 0; nt < 4; nt++)
                    acc[mt][nt] = __builtin_amdgcn_mfma_f32_16x16x32_bf16(
                        af[mt], bfrag[nt], acc[mt][nt], 0, 0, 0);
            __builtin_amdgcn_s_setprio(0);
        }
    }

    // ---- epilogue: D col(n=ow)=lane&15, row=quad*4+reg ----
    const int owc = ow0 + l15;
    if (owc < 110) {
        float* ob = out + b * 1548800 + wco * 64 * 12100;   // 128*12100 per batch
        #pragma unroll
        for (int mt = 0; mt < 4; mt++) {
            #pragma unroll
            for (int nt = 0; nt < 4; nt++) {
                const int oh = oh0 + woh * 4 + nt;
                if (oh < 110) {
                    #pragma unroll
                    for (int reg = 0; reg < 4; reg++) {
                        const int co = mt * 16 + quad * 4 + reg;
                        ob[(co * 110 + oh) * 110 + owc] = acc[mt][nt][reg];
                    }
                }
            }
        }
    }
}

extern "C" void kernel_launch(void* const* d_in, const int* in_sizes, int n_in,
                              void* d_out, int out_size, void* d_ws, size_t ws_size,
                              hipStream_t stream) {
    const float* x = (const float*)d_in[0];
    const float* W = (const float*)d_in[1];
    float* out = (float*)d_out;
    unsigned short* wp = (unsigned short*)d_ws;             // 147456 B

    wperm_kernel<<<288, 256, 0, stream>>>(W, wp);
    conv_mfma<<<32 * 49, 512, 0, stream>>>(x, wp, out);
}